// Round 1
// baseline (560.310 us; speedup 1.0000x reference)
//
#include <hip/hip_runtime.h>
#include <hip/hip_bf16.h>
#include <math.h>

// Problem constants (fixed by the reference)
#define NN 1024      // proposals
#define DAPP 1024    // appearance dim
#define DK 64        // key dim
#define DG 64        // geo dim
#define NR 16        // relations

typedef __bf16 bf16x8 __attribute__((ext_vector_type(8)));
typedef float f32x4 __attribute__((ext_vector_type(4)));

// ---------------- ws layout (bytes) ----------------
// fab  : bf16 [1024][1024]        @ OFF_FAB   (2 MB)
// Wb   : bf16 [3][16][64][1024]   @ OFF_WB    (6 MB)   (K,Q,V stacked; row j = proj*1024 + r*64 + d)
// Kb   : bf16 [16][1024][64]      @ OFF_KB    (2 MB)
// Qb   : bf16 [16][1024][64]      @ OFF_QB    (2 MB)
// V    : f32  [16][1024][64]      @ OFF_V     (4 MB)
// S    : f32  [16][1024][1024]    @ OFF_S     (64 MB)  scores -> w_mn (in place)
// stats: f32x2 [16*1024]          @ OFF_ST    (128 KB)
static constexpr size_t OFF_FAB = 0;
static constexpr size_t OFF_WB  = OFF_FAB + (size_t)NN * DAPP * 2;
static constexpr size_t OFF_KB  = OFF_WB + (size_t)3 * NR * DK * DAPP * 2;
static constexpr size_t OFF_QB  = OFF_KB + (size_t)NR * NN * DK * 2;
static constexpr size_t OFF_V   = OFF_QB + (size_t)NR * NN * DK * 2;
static constexpr size_t OFF_S   = OFF_V + (size_t)NR * NN * DK * 4;
static constexpr size_t OFF_ST  = OFF_S + (size_t)NR * NN * NN * 4;

// ---------------- K0: cast f_a and W{K,Q,V} to bf16 ----------------
__global__ __launch_bounds__(256) void cast_kernel(
    const float* __restrict__ fa, const float* __restrict__ wk,
    const float* __restrict__ wq, const float* __restrict__ wv,
    __bf16* __restrict__ fab, __bf16* __restrict__ wb) {
  int i = blockIdx.x * 256 + threadIdx.x;  // 0 .. 4M-1
  const int M1 = NN * DAPP;                // 1M
  if (i < M1) {
    fab[i] = (__bf16)fa[i];
  } else {
    int j = i - M1;                        // 0 .. 3M-1
    int p = j >> 20;
    int o = j & (M1 - 1);
    const float* src = (p == 0) ? wk : ((p == 1) ? wq : wv);
    wb[j] = (__bf16)src[o];
  }
}

// ---------------- K1: KQV projection, bf16 MFMA, fused bias ----------------
// C[n, j] = sum_f fab[n,f] * Wb[j,f],  j in [0,3072)
// per wave: 32x32 output tile via 2x2 of 16x16x32 MFMAs, K loop 1024
__global__ __launch_bounds__(256) void kqv_kernel(
    const __bf16* __restrict__ fab, const __bf16* __restrict__ wb,
    const float* __restrict__ kbias, const float* __restrict__ qbias,
    const float* __restrict__ vbias,
    __bf16* __restrict__ Kb, __bf16* __restrict__ Qb, float* __restrict__ V) {
  int wave = blockIdx.x * 4 + (threadIdx.x >> 6);  // 0..3071
  int l = threadIdx.x & 63;
  int nt = wave / 96;        // 32 n-tiles
  int jt = wave % 96;        // 96 j-tiles
  int n0 = nt * 32, j0 = jt * 32;
  int ra = l & 15;
  int ko = (l >> 4) * 8;

  f32x4 acc[2][2] = {};
  for (int k0 = 0; k0 < DAPP; k0 += 32) {
    bf16x8 a0 = *(const bf16x8*)(fab + (size_t)(n0 + ra) * DAPP + k0 + ko);
    bf16x8 a1 = *(const bf16x8*)(fab + (size_t)(n0 + 16 + ra) * DAPP + k0 + ko);
    bf16x8 b0 = *(const bf16x8*)(wb + (size_t)(j0 + ra) * DAPP + k0 + ko);
    bf16x8 b1 = *(const bf16x8*)(wb + (size_t)(j0 + 16 + ra) * DAPP + k0 + ko);
    acc[0][0] = __builtin_amdgcn_mfma_f32_16x16x32_bf16(a0, b0, acc[0][0], 0, 0, 0);
    acc[0][1] = __builtin_amdgcn_mfma_f32_16x16x32_bf16(a0, b1, acc[0][1], 0, 0, 0);
    acc[1][0] = __builtin_amdgcn_mfma_f32_16x16x32_bf16(a1, b0, acc[1][0], 0, 0, 0);
    acc[1][1] = __builtin_amdgcn_mfma_f32_16x16x32_bf16(a1, b1, acc[1][1], 0, 0, 0);
  }

  // C/D layout: col = lane&15, row = (lane>>4)*4 + reg
  #pragma unroll
  for (int i = 0; i < 2; i++) {
    #pragma unroll
    for (int jj = 0; jj < 2; jj++) {
      #pragma unroll
      for (int q = 0; q < 4; q++) {
        int n = n0 + i * 16 + (l >> 4) * 4 + q;
        int col = j0 + jj * 16 + (l & 15);
        int proj = col >> 10;
        int rd = col & 1023;          // r*64 + d
        int r = rd >> 6, d = rd & 63;
        float v = acc[i][jj][q];
        size_t oidx = ((size_t)r * NN + n) * DK + d;
        if (proj == 0)      Kb[oidx] = (__bf16)(v + kbias[rd]);
        else if (proj == 1) Qb[oidx] = (__bf16)(v + qbias[rd]);
        else                V[oidx] = v + vbias[rd];
      }
    }
  }
}

// ---------------- K2: scores S[r,n,m] = (K_rn . Q_rm) / 8, bf16 MFMA ----------------
__global__ __launch_bounds__(256) void scores_kernel(
    const __bf16* __restrict__ Kb, const __bf16* __restrict__ Qb,
    float* __restrict__ S) {
  int wave = blockIdx.x * 4 + (threadIdx.x >> 6);  // 0..16383
  int r = wave >> 10;
  int idx = wave & 1023;
  int n0 = (idx >> 5) * 32;
  int m0 = (idx & 31) * 32;
  int l = threadIdx.x & 63;
  int ra = l & 15;
  int ko = (l >> 4) * 8;
  const __bf16* Kr = Kb + (size_t)r * NN * DK;
  const __bf16* Qr = Qb + (size_t)r * NN * DK;

  f32x4 acc[2][2] = {};
  #pragma unroll
  for (int k0 = 0; k0 < DK; k0 += 32) {
    bf16x8 a0 = *(const bf16x8*)(Kr + (n0 + ra) * DK + k0 + ko);
    bf16x8 a1 = *(const bf16x8*)(Kr + (n0 + 16 + ra) * DK + k0 + ko);
    bf16x8 b0 = *(const bf16x8*)(Qr + (m0 + ra) * DK + k0 + ko);
    bf16x8 b1 = *(const bf16x8*)(Qr + (m0 + 16 + ra) * DK + k0 + ko);
    acc[0][0] = __builtin_amdgcn_mfma_f32_16x16x32_bf16(a0, b0, acc[0][0], 0, 0, 0);
    acc[0][1] = __builtin_amdgcn_mfma_f32_16x16x32_bf16(a0, b1, acc[0][1], 0, 0, 0);
    acc[1][0] = __builtin_amdgcn_mfma_f32_16x16x32_bf16(a1, b0, acc[1][0], 0, 0, 0);
    acc[1][1] = __builtin_amdgcn_mfma_f32_16x16x32_bf16(a1, b1, acc[1][1], 0, 0, 0);
  }

  #pragma unroll
  for (int i = 0; i < 2; i++) {
    #pragma unroll
    for (int jj = 0; jj < 2; jj++) {
      #pragma unroll
      for (int q = 0; q < 4; q++) {
        int n = n0 + i * 16 + (l >> 4) * 4 + q;
        int m = m0 + jj * 16 + (l & 15);
        S[((size_t)r * NN + n) * NN + m] = acc[i][jj][q] * 0.125f;
      }
    }
  }
}

// ---------------- K3: geometric gate, fp32; S += log(max(lin, 1e-6)) ----------------
// block = (n, 256-m chunk); thread <-> m. pe streamed fp32 (precision matters near clip).
__global__ __launch_bounds__(256) void gate_kernel(
    const float* __restrict__ pe, const float* __restrict__ WGw,
    const float* __restrict__ WGb, float* __restrict__ S) {
  __shared__ float4 wgt[16][16];  // [g4][r] = WGw[r][4*g4 .. 4*g4+3]
  __shared__ float wgb[16];
  int t = threadIdx.x;
  {
    int g4 = t >> 4, r = t & 15;
    wgt[g4][r] = ((const float4*)WGw)[r * 16 + g4];
    if (t < 16) wgb[t] = WGb[t];
  }
  __syncthreads();

  int n = blockIdx.x >> 2;
  int m = ((blockIdx.x & 3) << 8) + t;
  const float4* pe4 = (const float4*)(pe + ((size_t)n * NN + m) * DG);

  float acc[16];
  #pragma unroll
  for (int r = 0; r < 16; r++) acc[r] = wgb[r];

  #pragma unroll
  for (int g4 = 0; g4 < 16; g4++) {
    float4 p = pe4[g4];
    #pragma unroll
    for (int r = 0; r < 16; r++) {
      float4 w = wgt[g4][r];
      acc[r] += p.x * w.x + p.y * w.y + p.z * w.z + p.w * w.w;
    }
  }

  size_t base = (size_t)n * NN + m;
  #pragma unroll
  for (int r = 0; r < 16; r++) {
    float lg = __logf(fmaxf(acc[r], 1e-6f));
    size_t idx = (size_t)r * NN * NN + base;
    S[idx] += lg;
  }
}

// ---------------- K4: per-(r,n) row max and sum-exp ----------------
__global__ __launch_bounds__(256) void stats_kernel(
    const float* __restrict__ S, float2* __restrict__ stats) {
  int row = blockIdx.x * 4 + (threadIdx.x >> 6);  // 0..16383 = r*1024+n
  int l = threadIdx.x & 63;
  const float* Sp = S + (size_t)row * NN;
  float v[16];
  float mx = -1e30f;
  #pragma unroll
  for (int i = 0; i < 16; i++) {
    v[i] = Sp[l + 64 * i];
    mx = fmaxf(mx, v[i]);
  }
  #pragma unroll
  for (int off = 32; off >= 1; off >>= 1) mx = fmaxf(mx, __shfl_xor(mx, off, 64));
  float sm = 0.f;
  #pragma unroll
  for (int i = 0; i < 16; i++) sm += __expf(v[i] - mx);
  #pragma unroll
  for (int off = 32; off >= 1; off >>= 1) sm += __shfl_xor(sm, off, 64);
  if (l == 0) stats[row] = make_float2(mx, sm);
}

// ---------------- K5: out[n, r*64+d] = sum_m softmax * V[r,m,d] + f_a ----------------
// block: (r, 32-n tile), loop m in 64-chunks. P^T and V tiles in LDS, fp32 FMA.
__global__ __launch_bounds__(256) void pv_kernel(
    const float* __restrict__ S, const float2* __restrict__ stats,
    const float* __restrict__ V, const float* __restrict__ fa,
    float* __restrict__ out) {
  int r = blockIdx.x >> 5;
  int n0 = (blockIdx.x & 31) * 32;
  __shared__ float Pt[64][36];   // [m_local][n_local], padded
  __shared__ float Vt[64][68];   // [m_local][d], padded
  __shared__ float2 st[32];
  int t = threadIdx.x;
  if (t < 32) st[t] = stats[r * NN + n0 + t];

  int d0 = (t & 15) * 4;
  int nl0 = (t >> 4) * 2;
  float acc[2][4] = {};

  for (int m0 = 0; m0 < NN; m0 += 64) {
    __syncthreads();
    // stage P^T = exp(S - mx): thread loads 8 m's of one n-row
    {
      int nl = t >> 3;
      int ml = (t & 7) * 8;
      const float* sp = S + ((size_t)r * NN + n0 + nl) * NN + m0 + ml;
      float mxn = st[nl].x;
      #pragma unroll
      for (int u = 0; u < 8; u++) Pt[ml + u][nl] = __expf(sp[u] - mxn);
    }
    // stage V tile
    {
      int ml = t >> 2;
      int dq = (t & 3) * 16;
      const float* vp = V + ((size_t)r * NN + m0 + ml) * DK + dq;
      #pragma unroll
      for (int u = 0; u < 4; u++) {
        float4 vv = ((const float4*)vp)[u];
        *(float4*)&Vt[ml][dq + u * 4] = vv;
      }
    }
    __syncthreads();
    #pragma unroll 8
    for (int ml = 0; ml < 64; ml++) {
      float a0 = Pt[ml][nl0];
      float a1 = Pt[ml][nl0 + 1];
      float4 vv = *(const float4*)&Vt[ml][d0];
      acc[0][0] += a0 * vv.x; acc[0][1] += a0 * vv.y;
      acc[0][2] += a0 * vv.z; acc[0][3] += a0 * vv.w;
      acc[1][0] += a1 * vv.x; acc[1][1] += a1 * vv.y;
      acc[1][2] += a1 * vv.z; acc[1][3] += a1 * vv.w;
    }
  }

  #pragma unroll
  for (int i = 0; i < 2; i++) {
    int n = n0 + nl0 + i;
    float rs = 1.0f / st[nl0 + i].y;
    int col = r * DK + d0;
    const float4 f = *(const float4*)(fa + (size_t)n * DAPP + col);
    float4 o;
    o.x = acc[i][0] * rs + f.x;
    o.y = acc[i][1] * rs + f.y;
    o.z = acc[i][2] * rs + f.z;
    o.w = acc[i][3] * rs + f.w;
    *(float4*)(out + (size_t)n * DAPP + col) = o;
  }
}

// ---------------- launch ----------------
extern "C" void kernel_launch(void* const* d_in, const int* in_sizes, int n_in,
                              void* d_out, int out_size, void* d_ws, size_t ws_size,
                              hipStream_t stream) {
  const float* fa  = (const float*)d_in[0];
  const float* pe  = (const float*)d_in[1];
  const float* WGw = (const float*)d_in[2];
  const float* WGb = (const float*)d_in[3];
  const float* WKw = (const float*)d_in[4];
  const float* WKb = (const float*)d_in[5];
  const float* WQw = (const float*)d_in[6];
  const float* WQb = (const float*)d_in[7];
  const float* WVw = (const float*)d_in[8];
  const float* WVb = (const float*)d_in[9];
  float* out = (float*)d_out;

  char* ws = (char*)d_ws;
  __bf16* fab = (__bf16*)(ws + OFF_FAB);
  __bf16* wb  = (__bf16*)(ws + OFF_WB);
  __bf16* Kb  = (__bf16*)(ws + OFF_KB);
  __bf16* Qb  = (__bf16*)(ws + OFF_QB);
  float*  V   = (float*)(ws + OFF_V);
  float*  S   = (float*)(ws + OFF_S);
  float2* st  = (float2*)(ws + OFF_ST);

  // K0: cast (4M elems)
  cast_kernel<<<(4 * NN * DAPP / (NN * DAPP)) * (NN * DAPP / 256) , 256, 0, stream>>>(
      fa, WKw, WQw, WVw, fab, wb);
  // K1: KQV projection (3072 waves = 768 blocks)
  kqv_kernel<<<768, 256, 0, stream>>>(fab, wb, WKb, WQb, WVb, Kb, Qb, V);
  // K2: scores (16384 waves = 4096 blocks)
  scores_kernel<<<4096, 256, 0, stream>>>(Kb, Qb, S);
  // K3: gate (1024 n x 4 m-chunks)
  gate_kernel<<<4096, 256, 0, stream>>>(pe, WGw, WGb, S);
  // K4: row stats (16384 rows, 4 per block)
  stats_kernel<<<4096, 256, 0, stream>>>(S, st);
  // K5: PV + residual (16 r x 32 n-tiles)
  pv_kernel<<<512, 256, 0, stream>>>(S, st, V, fa, out);
}